// Round 5
// baseline (6967.550 us; speedup 1.0000x reference)
//
#include <hip/hip_runtime.h>

#define NTOK   8192
#define DIM    256
#define NDEPTH 4
#define KROWS  8193   // storage stride: codebooks[4][8193][256]
#define KARG   8192   // argmin domain: padding row DROPPED (ref uses cb[:-1])
#define TM     16     // tokens per argmin block

// ---------------- seed fp64 residual with exact cast of x ----------------
__global__ void cast_kernel(const float* __restrict__ x, double* __restrict__ r64) {
    int i = blockIdx.x * 256 + threadIdx.x;
    r64[i] = (double)x[i];
}

// ---------------- cnorm: ||c_j||^2 in double, per depth, rows [0, KARG) ----------------
__global__ void cnorm_kernel(const float* __restrict__ cbs, double* __restrict__ cnorm) {
    int d    = blockIdx.y;
    int row  = blockIdx.x * 4 + (threadIdx.x >> 6);   // 2048 blocks * 4 waves = 8192 rows
    int lane = threadIdx.x & 63;
    const float* c = cbs + ((size_t)d * KROWS + row) * DIM;
    float4 v = *(const float4*)(c + lane * 4);
    double s = (double)v.x * v.x + (double)v.y * v.y + (double)v.z * v.z + (double)v.w * v.w;
    #pragma unroll
    for (int o = 32; o > 0; o >>= 1) s += __shfl_down(s, o, 64);
    if (lane == 0) cnorm[(size_t)d * KARG + row] = s;
}

// ---------------- argmin over KARG codes for TM tokens per block, full fp64 ----------------
__global__ __launch_bounds__(256) void argmin_kernel(const double* __restrict__ rsrc,
                                                     const float* __restrict__ cb,
                                                     const double* __restrict__ cnorm,
                                                     int* __restrict__ idx_out) {
    __shared__ double rs[TM][DIM];      // 32 KB: fp64 residuals of this block's tokens
    __shared__ double sbest[256];
    __shared__ int    sbidx[256];
    const int tid = threadIdx.x;
    const int t0  = blockIdx.x * TM;

    for (int r = 0; r < TM; ++r)
        rs[r][tid] = rsrc[(size_t)(t0 + r) * DIM + tid];   // coalesced 8B
    __syncthreads();

    double best[TM];
    int    bestj[TM];
    #pragma unroll
    for (int t = 0; t < TM; ++t) { best[t] = 1e300; bestj[t] = 0; }

    for (int j0 = 0; j0 < KARG; j0 += 256) {               // 32 full iterations, no tail
        const int j = j0 + tid;
        const float* c = cb + (size_t)j * DIM;
        double acc[TM];
        #pragma unroll
        for (int t = 0; t < TM; ++t) acc[t] = 0.0;
        #pragma unroll 1
        for (int i = 0; i < DIM; i += 4) {
            float4 cv = *(const float4*)(c + i);
            double c0 = cv.x, c1 = cv.y, c2 = cv.z, c3 = cv.w;
            #pragma unroll
            for (int t = 0; t < TM; ++t) {
                acc[t] = fma(c3, rs[t][i + 3],
                         fma(c2, rs[t][i + 2],
                         fma(c1, rs[t][i + 1],
                         fma(c0, rs[t][i + 0], acc[t]))));
            }
        }
        double cn = cnorm[j];
        #pragma unroll
        for (int t = 0; t < TM; ++t) {
            double dist = cn - 2.0 * acc[t];          // ||r||^2 dropped (argmin-safe in fp64)
            if (dist < best[t]) { best[t] = dist; bestj[t] = j; }  // strict <: earliest j wins
        }
    }

    // per-token block reduction (tie -> smaller index)
    for (int t = 0; t < TM; ++t) {
        sbest[tid] = best[t]; sbidx[tid] = bestj[t];
        __syncthreads();
        for (int s = 128; s > 0; s >>= 1) {
            if (tid < s) {
                double ob = sbest[tid + s]; int oj = sbidx[tid + s];
                if (ob < sbest[tid] || (ob == sbest[tid] && oj < sbidx[tid])) {
                    sbest[tid] = ob; sbidx[tid] = oj;
                }
            }
            __syncthreads();
        }
        if (tid == 0) idx_out[t0 + t] = sbidx[0];
        __syncthreads();
    }
}

// ---------------- update: fp64 residual (never rounded), fp32 agg/loss, codes ----------------
__global__ void update_kernel(const float* __restrict__ x, const float* __restrict__ cb,
                              const int* __restrict__ idxv, double* __restrict__ resid,
                              float* __restrict__ agg, double* __restrict__ lossSum,
                              float* __restrict__ codes_out, int is_first) {
    const int t = blockIdx.x;
    const int i = threadIdx.x;
    const int idx = idxv[t];
    const size_t off = (size_t)t * DIM + i;
    float q = cb[(size_t)idx * DIM + i];
    double r_old = resid[off];
    resid[off] = r_old - (double)q;                 // exact fp64 residual chain
    float a_new = is_first ? q : (agg[off] + q);
    agg[off] = a_new;
    float diff = x[off] - a_new;
    double v = (double)diff * (double)diff;
    #pragma unroll
    for (int o = 32; o > 0; o >>= 1) v += __shfl_down(v, o, 64);
    __shared__ double wsum[4];
    int wid = i >> 6, lane = i & 63;
    if (lane == 0) wsum[wid] = v;
    __syncthreads();
    if (i == 0) {
        atomicAdd(lossSum, wsum[0] + wsum[1] + wsum[2] + wsum[3]);
        codes_out[(size_t)t * NDEPTH] = (float)idx;   // indices stored as f32 values
    }
}

// ---------------- epilogue: STE output + commitment loss scalar ----------------
__global__ void final_kernel(const float* __restrict__ x, const float* __restrict__ agg,
                             float* __restrict__ out, const double* __restrict__ lossSum) {
    int gid = blockIdx.x * blockDim.x + threadIdx.x;
    size_t base = (size_t)gid * 4;
    if (base < (size_t)NTOK * DIM) {
        float4 av = *(const float4*)(agg + base);
        *(float4*)(out + base) = av;                 // x + (agg - x) == agg
    }
    if (gid == 0) {
        double s = (lossSum[0] + lossSum[1] + lossSum[2] + lossSum[3]) / (double)((size_t)NTOK * DIM);
        out[(size_t)NTOK * DIM] = (float)(0.25 * s / (double)NDEPTH);
    }
}

extern "C" void kernel_launch(void* const* d_in, const int* in_sizes, int n_in,
                              void* d_out, int out_size, void* d_ws, size_t ws_size,
                              hipStream_t stream) {
    const float* x   = (const float*)d_in[0];
    const float* cbs = (const float*)d_in[1];
    float* out = (float*)d_out;
    char* ws = (char*)d_ws;

    // ws layout: resid64 f64[2097152] (16 MB) | agg f32[2097152] (8 MB) | cnorm f64[4*8192] | idx | lossSum
    double* resid64 = (double*)(ws);
    float*  agg     = (float*)(ws + 16777216);
    double* cnorm   = (double*)(ws + 25165824);
    int*    idxbuf  = (int*)(ws + 25165824 + (size_t)NDEPTH * KARG * 8);            // +262,144
    double* lossSum = (double*)(ws + 25165824 + (size_t)NDEPTH * KARG * 8 + 32768);

    hipMemsetAsync(lossSum, 0, NDEPTH * sizeof(double), stream);
    cast_kernel<<<NTOK * DIM / 256, 256, 0, stream>>>(x, resid64);
    cnorm_kernel<<<dim3(KARG / 4, NDEPTH), 256, 0, stream>>>(cbs, cnorm);

    float* codes_base = out + (size_t)NTOK * DIM + 1;
    for (int d = 0; d < NDEPTH; ++d) {
        const float* cbd = cbs + (size_t)d * KROWS * DIM;
        argmin_kernel<<<NTOK / TM, 256, 0, stream>>>(resid64, cbd, cnorm + (size_t)d * KARG, idxbuf);
        update_kernel<<<NTOK, 256, 0, stream>>>(x, cbd, idxbuf, resid64, agg,
                                                lossSum + d, codes_base + d, d == 0 ? 1 : 0);
    }
    final_kernel<<<(NTOK * DIM / 4 + 255) / 256, 256, 0, stream>>>(x, agg, out, lossSum);
}

// Round 6
// 5145.948 us; speedup vs baseline: 1.3540x; 1.3540x over previous
//
#include <hip/hip_runtime.h>

#define NTOK   8192
#define DIM    256
#define NDEPTH 4
#define KROWS  8193   // storage stride of codebooks input
#define KARG   8192   // argmin domain (padding row dropped)
#define TT     32     // tokens per argmin_f32 block
#define JHALF  4096   // codes per slice (2 slices)
#define EPSGAP 2e-3f  // >= 4x worst-case fp32 distance error

// ---------------- seed fp64 residual with exact cast of x ----------------
__global__ void cast_kernel(const float* __restrict__ x, double* __restrict__ r64) {
    int i = blockIdx.x * 256 + threadIdx.x;
    r64[i] = (double)x[i];
}

// ---------------- cnorm in fp64 (+ fp32 rounding), rows [0, KARG) ----------------
__global__ void cnorm_kernel(const float* __restrict__ cbs, double* __restrict__ cnorm64,
                             float* __restrict__ cnorm32) {
    int d    = blockIdx.y;
    int row  = blockIdx.x * 4 + (threadIdx.x >> 6);
    int lane = threadIdx.x & 63;
    const float* c = cbs + ((size_t)d * KROWS + row) * DIM;
    float4 v = *(const float4*)(c + lane * 4);
    double s = (double)v.x * v.x + (double)v.y * v.y + (double)v.z * v.z + (double)v.w * v.w;
    #pragma unroll
    for (int o = 32; o > 0; o >>= 1) s += __shfl_down(s, o, 64);
    if (lane == 0) {
        cnorm64[(size_t)d * KARG + row] = s;
        cnorm32[(size_t)d * KARG + row] = (float)s;
    }
}

// ---------------- transpose codebooks: cbs[d][j][i] -> cbT[d][i][j], j < KARG ----------------
__global__ void transpose_cb(const float* __restrict__ cbs, float* __restrict__ cbT) {
    __shared__ float tile[64][65];
    int d  = blockIdx.z;
    int i0 = blockIdx.y * 64;
    int j0 = blockIdx.x * 64;
    int c  = threadIdx.x & 63;
    int rq = threadIdx.x >> 6;
    for (int r = rq; r < 64; r += 4)
        tile[r][c] = cbs[((size_t)d * KROWS + j0 + r) * DIM + i0 + c];
    __syncthreads();
    for (int r = rq; r < 64; r += 4)
        cbT[((size_t)d * DIM + i0 + r) * KARG + j0 + c] = tile[c][r];
}

// ---------------- fp32 prefilter: per token (min1, j1, min2) over a j-slice ----------------
__global__ __launch_bounds__(256) void argmin_f32(const double* __restrict__ rsrc,
                                                  const float* __restrict__ cbT_d,
                                                  const float* __restrict__ cn32_d,
                                                  float* __restrict__ sM1, int* __restrict__ sJ1,
                                                  float* __restrict__ sM2) {
    __shared__ float rsT[DIM][TT];        // 32 KB
    __shared__ float ctile[32][128];      // 16 KB
    const int tid   = threadIdx.x;
    const int tile  = blockIdx.x >> 1;
    const int slice = blockIdx.x & 1;
    const int t0    = tile * TT;

    for (int p = 0; p < TT; ++p)          // token t0+p, dim tid (coalesced 8B)
        rsT[tid][p] = (float)rsrc[(size_t)(t0 + p) * DIM + tid];

    const int tg = tid >> 5;              // 8 token groups of 4
    const int jg = tid & 31;              // 32 j groups of 4
    const float INF = __int_as_float(0x7f800000);
    float m1[4] = {INF, INF, INF, INF}, m2[4] = {INF, INF, INF, INF};
    int   j1v[4] = {0, 0, 0, 0};

    for (int ch = 0; ch < 32; ++ch) {
        const int jbase = slice * JHALF + ch * 128;
        float4 acc[4];
        #pragma unroll
        for (int t = 0; t < 4; ++t) acc[t] = make_float4(0.f, 0.f, 0.f, 0.f);

        for (int i0 = 0; i0 < DIM; i0 += 32) {
            __syncthreads();
            #pragma unroll
            for (int c = 0; c < 4; ++c) {              // stage 32x128 floats, coalesced
                int fi = c * 1024 + tid * 4;
                int il = fi >> 7, jl = fi & 127;
                *(float4*)&ctile[il][jl] =
                    *(const float4*)(cbT_d + (size_t)(i0 + il) * KARG + jbase + jl);
            }
            __syncthreads();
            #pragma unroll 8
            for (int ii = 0; ii < 32; ++ii) {
                float4 rv = *(const float4*)&rsT[i0 + ii][tg * 4];
                float4 cv = *(const float4*)&ctile[ii][jg * 4];
                acc[0].x = fmaf(rv.x, cv.x, acc[0].x);
                acc[0].y = fmaf(rv.x, cv.y, acc[0].y);
                acc[0].z = fmaf(rv.x, cv.z, acc[0].z);
                acc[0].w = fmaf(rv.x, cv.w, acc[0].w);
                acc[1].x = fmaf(rv.y, cv.x, acc[1].x);
                acc[1].y = fmaf(rv.y, cv.y, acc[1].y);
                acc[1].z = fmaf(rv.y, cv.z, acc[1].z);
                acc[1].w = fmaf(rv.y, cv.w, acc[1].w);
                acc[2].x = fmaf(rv.z, cv.x, acc[2].x);
                acc[2].y = fmaf(rv.z, cv.y, acc[2].y);
                acc[2].z = fmaf(rv.z, cv.z, acc[2].z);
                acc[2].w = fmaf(rv.z, cv.w, acc[2].w);
                acc[3].x = fmaf(rv.w, cv.x, acc[3].x);
                acc[3].y = fmaf(rv.w, cv.y, acc[3].y);
                acc[3].z = fmaf(rv.w, cv.z, acc[3].z);
                acc[3].w = fmaf(rv.w, cv.w, acc[3].w);
            }
        }
        #pragma unroll
        for (int t = 0; t < 4; ++t) {
            float a[4] = {acc[t].x, acc[t].y, acc[t].z, acc[t].w};
            #pragma unroll
            for (int q = 0; q < 4; ++q) {
                int j = jbase + jg * 4 + q;
                float dv = cn32_d[j] - 2.0f * a[q];
                if (dv < m1[t]) { m2[t] = m1[t]; m1[t] = dv; j1v[t] = j; }
                else if (dv < m2[t]) { m2[t] = dv; }
            }
        }
    }

    #pragma unroll
    for (int off = 16; off > 0; off >>= 1) {
        #pragma unroll
        for (int t = 0; t < 4; ++t) {
            float om1 = __shfl_xor(m1[t], off, 64);
            int   oj  = __shfl_xor(j1v[t], off, 64);
            float om2 = __shfl_xor(m2[t], off, 64);
            if (om1 < m1[t]) { m2[t] = fminf(m1[t], om2); m1[t] = om1; j1v[t] = oj; }
            else             { m2[t] = fminf(om1, m2[t]); }
        }
    }
    if (jg == 0) {
        #pragma unroll
        for (int t = 0; t < 4; ++t) {
            int tk = t0 + tg * 4 + t;
            sM1[slice * NTOK + tk] = m1[t];
            sJ1[slice * NTOK + tk] = j1v[t];
            sM2[slice * NTOK + tk] = m2[t];
        }
    }
}

// ---------------- merge slices; certain -> idx, uncertain -> flag list ----------------
__global__ void merge_flag(const float* __restrict__ sM1, const int* __restrict__ sJ1,
                           const float* __restrict__ sM2, int* __restrict__ idxv,
                           int* __restrict__ flagList, int* __restrict__ flagCount) {
    int t = blockIdx.x * 256 + threadIdx.x;
    float a1 = sM1[t], b1 = sM1[NTOK + t];
    int   aj = sJ1[t], bj = sJ1[NTOK + t];
    float a2 = sM2[t], b2 = sM2[NTOK + t];
    float m1, m2; int j1;
    if (b1 < a1) { m1 = b1; j1 = bj; m2 = fminf(a1, b2); }
    else         { m1 = a1; j1 = aj; m2 = fminf(b1, a2); }
    if (m2 - m1 <= EPSGAP) {
        int pos = atomicAdd(flagCount, 1);
        flagList[pos] = t;
    } else {
        idxv[t] = j1;
    }
}

// ---------------- exact fp64 re-check for flagged tokens (4 per block) ----------------
__global__ __launch_bounds__(256) void recheck64(const double* __restrict__ rsrc,
                                                 const float* __restrict__ cb,
                                                 const double* __restrict__ cnorm,
                                                 const int* __restrict__ flagList,
                                                 const int* __restrict__ flagCount,
                                                 int* __restrict__ idx_out) {
    const int count = *flagCount;
    const int base  = blockIdx.x * 4;
    if (base >= count) return;
    const int nt  = min(4, count - base);
    const int tid = threadIdx.x;
    __shared__ double rs[4][DIM];
    __shared__ double sbest[256];
    __shared__ int    sbidx[256];
    __shared__ int    toks[4];
    if (tid < 4) toks[tid] = flagList[base + min(tid, nt - 1)];
    __syncthreads();
    for (int r = 0; r < nt; ++r)
        rs[r][tid] = rsrc[(size_t)toks[r] * DIM + tid];
    __syncthreads();

    double best[4] = {1e300, 1e300, 1e300, 1e300};
    int    bestj[4] = {0, 0, 0, 0};
    for (int j0 = 0; j0 < KARG; j0 += 256) {
        const int j = j0 + tid;
        const float* c = cb + (size_t)j * DIM;
        double acc[4] = {0.0, 0.0, 0.0, 0.0};
        #pragma unroll 1
        for (int i = 0; i < DIM; i += 4) {
            float4 cv = *(const float4*)(c + i);
            double c0 = cv.x, c1 = cv.y, c2 = cv.z, c3 = cv.w;
            #pragma unroll
            for (int t = 0; t < 4; ++t) {
                acc[t] = fma(c3, rs[t][i + 3],
                         fma(c2, rs[t][i + 2],
                         fma(c1, rs[t][i + 1],
                         fma(c0, rs[t][i + 0], acc[t]))));
            }
        }
        double cn = cnorm[j];
        #pragma unroll
        for (int t = 0; t < 4; ++t) {
            double dist = cn - 2.0 * acc[t];
            if (dist < best[t]) { best[t] = dist; bestj[t] = j; }
        }
    }
    for (int t = 0; t < nt; ++t) {
        sbest[tid] = best[t]; sbidx[tid] = bestj[t];
        __syncthreads();
        for (int s = 128; s > 0; s >>= 1) {
            if (tid < s) {
                double ob = sbest[tid + s]; int oj = sbidx[tid + s];
                if (ob < sbest[tid] || (ob == sbest[tid] && oj < sbidx[tid])) {
                    sbest[tid] = ob; sbidx[tid] = oj;
                }
            }
            __syncthreads();
        }
        if (tid == 0) idx_out[toks[t]] = sbidx[0];
        __syncthreads();
    }
}

// ---------------- update: fp64 residual, agg accumulated directly into out, loss ----------------
__global__ void update_kernel(const float* __restrict__ x, const float* __restrict__ cb,
                              const int* __restrict__ idxv, double* __restrict__ resid,
                              float* __restrict__ out, double* __restrict__ lossSum,
                              float* __restrict__ codes_out, int is_first) {
    const int t = blockIdx.x;
    const int i = threadIdx.x;
    const int idx = idxv[t];
    const size_t off = (size_t)t * DIM + i;
    float q = cb[(size_t)idx * DIM + i];
    double r_old = resid[off];
    resid[off] = r_old - (double)q;                 // exact fp64 residual chain
    float a_new = is_first ? q : (out[off] + q);    // out doubles as agg (STE: out == agg)
    out[off] = a_new;
    float diff = x[off] - a_new;
    double v = (double)diff * (double)diff;
    #pragma unroll
    for (int o = 32; o > 0; o >>= 1) v += __shfl_down(v, o, 64);
    __shared__ double wsum[4];
    int wid = i >> 6, lane = i & 63;
    if (lane == 0) wsum[wid] = v;
    __syncthreads();
    if (i == 0) {
        atomicAdd(lossSum, wsum[0] + wsum[1] + wsum[2] + wsum[3]);
        codes_out[(size_t)t * NDEPTH] = (float)idx;
    }
}

// ---------------- epilogue: commitment loss scalar ----------------
__global__ void final_kernel(float* __restrict__ out, const double* __restrict__ lossSum) {
    if (threadIdx.x == 0) {
        double s = (lossSum[0] + lossSum[1] + lossSum[2] + lossSum[3]) / (double)((size_t)NTOK * DIM);
        out[(size_t)NTOK * DIM] = (float)(0.25 * s / (double)NDEPTH);
    }
}

extern "C" void kernel_launch(void* const* d_in, const int* in_sizes, int n_in,
                              void* d_out, int out_size, void* d_ws, size_t ws_size,
                              hipStream_t stream) {
    const float* x   = (const float*)d_in[0];
    const float* cbs = (const float*)d_in[1];
    float* out = (float*)d_out;
    char* ws = (char*)d_ws;

    double* resid64  = (double*)(ws);                       // 16,777,216
    float*  cbT      = (float*)(ws + 16777216);             // 33,554,432
    double* cnorm64  = (double*)(ws + 50331648);            //    262,144
    float*  cnorm32  = (float*)(ws + 50593792);             //    131,072
    float*  sM1      = (float*)(ws + 50724864);             //     65,536
    int*    sJ1      = (int*)  (ws + 50790400);             //     65,536
    float*  sM2      = (float*)(ws + 50855936);             //     65,536
    int*    idxbuf   = (int*)  (ws + 50921472);             //     32,768
    int*    flagList = (int*)  (ws + 50954240);             //     32,768
    int*    flagCount= (int*)  (ws + 50987008);             //         16
    double* lossSum  = (double*)(ws + 50987024);            //         32

    hipMemsetAsync(lossSum, 0, NDEPTH * sizeof(double), stream);
    cast_kernel<<<NTOK * DIM / 256, 256, 0, stream>>>(x, resid64);
    cnorm_kernel<<<dim3(KARG / 4, NDEPTH), 256, 0, stream>>>(cbs, cnorm64, cnorm32);
    transpose_cb<<<dim3(KARG / 64, DIM / 64, NDEPTH), 256, 0, stream>>>(cbs, cbT);

    float* codes_base = out + (size_t)NTOK * DIM + 1;
    for (int d = 0; d < NDEPTH; ++d) {
        const float* cbd = cbs + (size_t)d * KROWS * DIM;
        hipMemsetAsync(flagCount, 0, sizeof(int), stream);
        argmin_f32<<<512, 256, 0, stream>>>(resid64, cbT + (size_t)d * DIM * KARG,
                                            cnorm32 + (size_t)d * KARG, sM1, sJ1, sM2);
        merge_flag<<<NTOK / 256, 256, 0, stream>>>(sM1, sJ1, sM2, idxbuf, flagList, flagCount);
        recheck64<<<NTOK / 4, 256, 0, stream>>>(resid64, cbd, cnorm64 + (size_t)d * KARG,
                                                flagList, flagCount, idxbuf);
        update_kernel<<<NTOK, 256, 0, stream>>>(x, cbd, idxbuf, resid64, out,
                                                lossSum + d, codes_base + d, d == 0 ? 1 : 0);
    }
    final_kernel<<<1, 64, 0, stream>>>(out, lossSum);
}

// Round 8
// 2578.900 us; speedup vs baseline: 2.7018x; 1.9954x over previous
//
#include <hip/hip_runtime.h>

#define NTOK   8192
#define DIM    256
#define NDEPTH 4
#define KROWS  8193     // storage stride of codebooks input
#define KARG   8192     // argmin domain (padding row dropped)
#define NSLICE 8        // code slices in MFMA argmin (1024 codes each)
#define FCAP   1024     // flagged-token capacity
#define EPSGAP 3e-3f    // >= 6x worst-case bf16-split distance error

typedef __attribute__((ext_vector_type(8))) short short8v;
typedef __attribute__((ext_vector_type(4))) float float4v;

__device__ __forceinline__ unsigned short f2bf(float f) {
    unsigned int u = __float_as_uint(f);
    unsigned int r = (u + 0x7FFFu + ((u >> 16) & 1u)) >> 16;
    return (unsigned short)r;
}

// fragment index helpers (16x16x32 bf16 MFMA layout, m89-verified family)
// A (codes):  m = j&15, k_local = i&31 with s = i>>5 ; lane = (k>>3)*16 + m ; e = k&7
// B (tokens): n = t&15, same k mapping.
__device__ __forceinline__ size_t fragIdx(int tile, int s, int lane, int e) {
    return ((((size_t)tile * 8 + s) * 64 + lane) * 8 + e);
}

// ---------------- seed fp64 residual ----------------
__global__ void cast_kernel(const float* __restrict__ x, double* __restrict__ r64) {
    int i = blockIdx.x * 256 + threadIdx.x;
    r64[i] = (double)x[i];
}

// ---------------- cnorm fp64 + fp32 ----------------
__global__ void cnorm_kernel(const float* __restrict__ cbs, double* __restrict__ cnorm64,
                             float* __restrict__ cnorm32) {
    int d    = blockIdx.y;
    int row  = blockIdx.x * 4 + (threadIdx.x >> 6);
    int lane = threadIdx.x & 63;
    const float* c = cbs + ((size_t)d * KROWS + row) * DIM;
    float4 v = *(const float4*)(c + lane * 4);
    double s = (double)v.x * v.x + (double)v.y * v.y + (double)v.z * v.z + (double)v.w * v.w;
    #pragma unroll
    for (int o = 32; o > 0; o >>= 1) s += __shfl_down(s, o, 64);
    if (lane == 0) {
        cnorm64[(size_t)d * KARG + row] = s;
        cnorm32[(size_t)d * KARG + row] = (float)s;
    }
}

// ---------------- codes -> bf16 hi/lo fragments (all depths, once) ----------------
__global__ void prep_codes(const float* __restrict__ cbs, unsigned short* __restrict__ chA,
                           unsigned short* __restrict__ clA) {
    int bid = blockIdx.x;              // d*8192 + j
    int d = bid >> 13, j = bid & 8191;
    int i = threadIdx.x;
    float v = cbs[((size_t)d * KROWS + j) * DIM + i];
    unsigned short hb = f2bf(v);
    float hf = __uint_as_float(((unsigned int)hb) << 16);
    unsigned short lb = f2bf(v - hf);
    int CT = j >> 4, m = j & 15;
    int s = i >> 5, kl = i & 31, g = kl >> 3, e = kl & 7;
    size_t base = (size_t)d * KARG * DIM;
    size_t idx = base + fragIdx(CT, s, g * 16 + m, e);
    chA[idx] = hb;
    clA[idx] = lb;
}

// ---------------- tokens(x) -> bf16 hi/lo fragments (depth 0) ----------------
__global__ void prep_tokens0(const float* __restrict__ x, unsigned short* __restrict__ rhB,
                             unsigned short* __restrict__ rlB) {
    int t = blockIdx.x, i = threadIdx.x;
    float v = x[(size_t)t * DIM + i];
    unsigned short hb = f2bf(v);
    float hf = __uint_as_float(((unsigned int)hb) << 16);
    unsigned short lb = f2bf(v - hf);
    int T = t >> 4, n = t & 15;
    int s = i >> 5, kl = i & 31, g = kl >> 3, e = kl & 7;
    size_t idx = fragIdx(T, s, g * 16 + n, e);
    rhB[idx] = hb;
    rlB[idx] = lb;
}

// ---------------- MFMA argmin: per slice of 1024 codes, (m1, j1, m2) per token ----------------
__global__ __launch_bounds__(512, 4) void argmin_mfma(const unsigned short* __restrict__ chA_d,
                                                      const unsigned short* __restrict__ clA_d,
                                                      const unsigned short* __restrict__ rhB,
                                                      const unsigned short* __restrict__ rlB,
                                                      const float* __restrict__ cn32_d,
                                                      float* __restrict__ sM1, int* __restrict__ sJ1,
                                                      float* __restrict__ sM2) {
    const int wave = threadIdx.x >> 6, lane = threadIdx.x & 63;
    const int tg = blockIdx.x >> 3, slice = blockIdx.x & 7;
    const int g4 = lane >> 4, col = lane & 15;
    const float INF = __int_as_float(0x7f800000);

    float M1[2] = {INF, INF}, M2[2] = {INF, INF};
    int   J1[2] = {0, 0};

    for (int cg = 0; cg < 16; ++cg) {
        const int CT0 = slice * 64 + cg * 4;
        float4v acc00 = {0,0,0,0}, acc01 = {0,0,0,0}, acc10 = {0,0,0,0}, acc11 = {0,0,0,0};
        float4v acc20 = {0,0,0,0}, acc21 = {0,0,0,0}, acc30 = {0,0,0,0}, acc31 = {0,0,0,0};
        #pragma unroll
        for (int s = 0; s < 8; ++s) {
            short8v ah0 = *(const short8v*)(chA_d + fragIdx(CT0 + 0, s, lane, 0));
            short8v ah1 = *(const short8v*)(chA_d + fragIdx(CT0 + 1, s, lane, 0));
            short8v ah2 = *(const short8v*)(chA_d + fragIdx(CT0 + 2, s, lane, 0));
            short8v ah3 = *(const short8v*)(chA_d + fragIdx(CT0 + 3, s, lane, 0));
            short8v al0 = *(const short8v*)(clA_d + fragIdx(CT0 + 0, s, lane, 0));
            short8v al1 = *(const short8v*)(clA_d + fragIdx(CT0 + 1, s, lane, 0));
            short8v al2 = *(const short8v*)(clA_d + fragIdx(CT0 + 2, s, lane, 0));
            short8v al3 = *(const short8v*)(clA_d + fragIdx(CT0 + 3, s, lane, 0));
            #pragma unroll
            for (int tt = 0; tt < 2; ++tt) {
                const int T = tg * 16 + wave * 2 + tt;
                short8v bh = *(const short8v*)(rhB + fragIdx(T, s, lane, 0));
                short8v bl = *(const short8v*)(rlB + fragIdx(T, s, lane, 0));
                float4v* a0 = tt ? &acc01 : &acc00;
                float4v* a1 = tt ? &acc11 : &acc10;
                float4v* a2 = tt ? &acc21 : &acc20;
                float4v* a3 = tt ? &acc31 : &acc30;
                *a0 = __builtin_amdgcn_mfma_f32_16x16x32_bf16(ah0, bh, *a0, 0, 0, 0);
                *a0 = __builtin_amdgcn_mfma_f32_16x16x32_bf16(ah0, bl, *a0, 0, 0, 0);
                *a0 = __builtin_amdgcn_mfma_f32_16x16x32_bf16(al0, bh, *a0, 0, 0, 0);
                *a1 = __builtin_amdgcn_mfma_f32_16x16x32_bf16(ah1, bh, *a1, 0, 0, 0);
                *a1 = __builtin_amdgcn_mfma_f32_16x16x32_bf16(ah1, bl, *a1, 0, 0, 0);
                *a1 = __builtin_amdgcn_mfma_f32_16x16x32_bf16(al1, bh, *a1, 0, 0, 0);
                *a2 = __builtin_amdgcn_mfma_f32_16x16x32_bf16(ah2, bh, *a2, 0, 0, 0);
                *a2 = __builtin_amdgcn_mfma_f32_16x16x32_bf16(ah2, bl, *a2, 0, 0, 0);
                *a2 = __builtin_amdgcn_mfma_f32_16x16x32_bf16(al2, bh, *a2, 0, 0, 0);
                *a3 = __builtin_amdgcn_mfma_f32_16x16x32_bf16(ah3, bh, *a3, 0, 0, 0);
                *a3 = __builtin_amdgcn_mfma_f32_16x16x32_bf16(ah3, bl, *a3, 0, 0, 0);
                *a3 = __builtin_amdgcn_mfma_f32_16x16x32_bf16(al3, bh, *a3, 0, 0, 0);
            }
        }
        // epilogue: dist = cn - 2*acc, update per-token (m1, j1, m2); j ascending per lane
        #pragma unroll
        for (int c = 0; c < 4; ++c) {
            const int jb = (CT0 + c) * 16 + g4 * 4;
            float4 cn = *(const float4*)(cn32_d + jb);
            #pragma unroll
            for (int tt = 0; tt < 2; ++tt) {
                const float4v* ac = (c == 0) ? (tt ? &acc01 : &acc00)
                                  : (c == 1) ? (tt ? &acc11 : &acc10)
                                  : (c == 2) ? (tt ? &acc21 : &acc20)
                                  :            (tt ? &acc31 : &acc30);
                float dv; int jv;
                dv = cn.x - 2.0f * (*ac)[0]; jv = jb + 0;
                if (dv < M1[tt]) { M2[tt] = M1[tt]; M1[tt] = dv; J1[tt] = jv; } else if (dv < M2[tt]) M2[tt] = dv;
                dv = cn.y - 2.0f * (*ac)[1]; jv = jb + 1;
                if (dv < M1[tt]) { M2[tt] = M1[tt]; M1[tt] = dv; J1[tt] = jv; } else if (dv < M2[tt]) M2[tt] = dv;
                dv = cn.z - 2.0f * (*ac)[2]; jv = jb + 2;
                if (dv < M1[tt]) { M2[tt] = M1[tt]; M1[tt] = dv; J1[tt] = jv; } else if (dv < M2[tt]) M2[tt] = dv;
                dv = cn.w - 2.0f * (*ac)[3]; jv = jb + 3;
                if (dv < M1[tt]) { M2[tt] = M1[tt]; M1[tt] = dv; J1[tt] = jv; } else if (dv < M2[tt]) M2[tt] = dv;
            }
        }
    }

    // reduce across the 4 lane-groups holding the same token column
    #pragma unroll
    for (int off = 16; off <= 32; off <<= 1) {
        #pragma unroll
        for (int tt = 0; tt < 2; ++tt) {
            float om1 = __shfl_xor(M1[tt], off, 64);
            int   oj  = __shfl_xor(J1[tt], off, 64);
            float om2 = __shfl_xor(M2[tt], off, 64);
            if (om1 < M1[tt] || (om1 == M1[tt] && oj < J1[tt])) {
                M2[tt] = fminf(M1[tt], om2); M1[tt] = om1; J1[tt] = oj;
            } else {
                M2[tt] = fminf(M2[tt], om1);
            }
        }
    }
    if (g4 == 0) {
        #pragma unroll
        for (int tt = 0; tt < 2; ++tt) {
            int t = (tg * 16 + wave * 2 + tt) * 16 + col;
            sM1[slice * NTOK + t] = M1[tt];
            sJ1[slice * NTOK + t] = J1[tt];
            sM2[slice * NTOK + t] = M2[tt];
        }
    }
}

// ---------------- merge 8 slices; always write best guess; flag near-ties ----------------
__global__ void merge_flag8(const float* __restrict__ sM1, const int* __restrict__ sJ1,
                            const float* __restrict__ sM2, int* __restrict__ idxv,
                            int* __restrict__ flagList, int* __restrict__ flagCount) {
    int t = blockIdx.x * 256 + threadIdx.x;
    float m1 = sM1[t], m2 = sM2[t];
    int   j1 = sJ1[t];
    #pragma unroll
    for (int s = 1; s < NSLICE; ++s) {
        float a1 = sM1[s * NTOK + t], a2 = sM2[s * NTOK + t];
        int   aj = sJ1[s * NTOK + t];
        if (a1 < m1) { m2 = fminf(m1, a2); m1 = a1; j1 = aj; }   // slices ascending: strict <
        else         { m2 = fminf(m2, a1); }
    }
    idxv[t] = j1;
    if (m2 - m1 <= EPSGAP) {
        int pos = atomicAdd(flagCount, 1);
        if (pos < FCAP) flagList[pos] = t;
    }
}

// ---------------- exact fp64 recheck, code-parallel: 8 blocks per flagged token ----------------
__global__ __launch_bounds__(256) void recheck_part(const double* __restrict__ rsrc,
                                                    const float* __restrict__ cb,
                                                    const double* __restrict__ cnorm,
                                                    const int* __restrict__ flagList,
                                                    const int* __restrict__ flagCount,
                                                    double* __restrict__ partD,
                                                    int* __restrict__ partJ) {
    const int slot = blockIdx.x >> 3;
    const int cnt  = min(*flagCount, FCAP);
    if (slot >= cnt) return;
    const int range = blockIdx.x & 7;
    const int tid   = threadIdx.x;
    const int tok   = flagList[slot];
    __shared__ double rs[DIM];
    __shared__ double sbest[256];
    __shared__ int    sbidx[256];
    rs[tid] = rsrc[(size_t)tok * DIM + tid];
    __syncthreads();

    double best = 1e300; int bestj = 0;
    for (int q = 0; q < 4; ++q) {
        const int j = range * 1024 + q * 256 + tid;
        const float* c = cb + (size_t)j * DIM;
        double acc = 0.0;
        #pragma unroll 1
        for (int i = 0; i < DIM; i += 4) {
            float4 cv = *(const float4*)(c + i);
            acc = fma((double)cv.w, rs[i + 3],
                  fma((double)cv.z, rs[i + 2],
                  fma((double)cv.y, rs[i + 1],
                  fma((double)cv.x, rs[i + 0], acc))));
        }
        double dist = cnorm[j] - 2.0 * acc;
        if (dist < best) { best = dist; bestj = j; }      // q ascending: strict <
    }
    sbest[tid] = best; sbidx[tid] = bestj;
    __syncthreads();
    for (int s = 128; s > 0; s >>= 1) {
        if (tid < s) {
            double ob = sbest[tid + s]; int oj = sbidx[tid + s];
            if (ob < sbest[tid] || (ob == sbest[tid] && oj < sbidx[tid])) {
                sbest[tid] = ob; sbidx[tid] = oj;
            }
        }
        __syncthreads();
    }
    if (tid == 0) { partD[slot * 8 + range] = sbest[0]; partJ[slot * 8 + range] = sbidx[0]; }
}

__global__ void recheck_merge(const int* __restrict__ flagList, const int* __restrict__ flagCount,
                              const double* __restrict__ partD, const int* __restrict__ partJ,
                              int* __restrict__ idxv) {
    int slot = blockIdx.x * 256 + threadIdx.x;
    int cnt  = min(*flagCount, FCAP);
    if (slot >= cnt) return;
    double best = partD[slot * 8]; int bestj = partJ[slot * 8];
    #pragma unroll
    for (int r = 1; r < 8; ++r) {
        double ob = partD[slot * 8 + r]; int oj = partJ[slot * 8 + r];
        if (ob < best) { best = ob; bestj = oj; }         // ranges ascending: strict <
    }
    idxv[flagList[slot]] = bestj;
}

// ---------------- update: fp64 residual + next-depth bf16 frags + agg/loss/codes ----------------
__global__ void update_kernel(const float* __restrict__ x, const float* __restrict__ cb,
                              const int* __restrict__ idxv, double* __restrict__ resid,
                              float* __restrict__ out, double* __restrict__ lossSum,
                              float* __restrict__ codes_out, unsigned short* __restrict__ rhB,
                              unsigned short* __restrict__ rlB, int is_first) {
    const int t = blockIdx.x;
    const int i = threadIdx.x;
    const int idx = idxv[t];
    const size_t off = (size_t)t * DIM + i;
    float q = cb[(size_t)idx * DIM + i];
    double r_new = resid[off] - (double)q;
    resid[off] = r_new;
    // next-depth token fragments
    float rv = (float)r_new;
    unsigned short hb = f2bf(rv);
    float hf = __uint_as_float(((unsigned int)hb) << 16);
    unsigned short lb = f2bf(rv - hf);
    {
        int T = t >> 4, n = t & 15;
        int s = i >> 5, kl = i & 31, g = kl >> 3, e = kl & 7;
        size_t fi = fragIdx(T, s, g * 16 + n, e);
        rhB[fi] = hb; rlB[fi] = lb;
    }
    float a_new = is_first ? q : (out[off] + q);    // out doubles as agg (STE: out == agg)
    out[off] = a_new;
    float diff = x[off] - a_new;
    double v = (double)diff * (double)diff;
    #pragma unroll
    for (int o = 32; o > 0; o >>= 1) v += __shfl_down(v, o, 64);
    __shared__ double wsum[4];
    int wid = i >> 6, lane = i & 63;
    if (lane == 0) wsum[wid] = v;
    __syncthreads();
    if (i == 0) {
        atomicAdd(lossSum, wsum[0] + wsum[1] + wsum[2] + wsum[3]);
        codes_out[(size_t)t * NDEPTH] = (float)idx;
    }
}

// ---------------- epilogue: commitment loss scalar ----------------
__global__ void final_kernel(float* __restrict__ out, const double* __restrict__ lossSum) {
    if (threadIdx.x == 0) {
        double s = (lossSum[0] + lossSum[1] + lossSum[2] + lossSum[3]) / (double)((size_t)NTOK * DIM);
        out[(size_t)NTOK * DIM] = (float)(0.25 * s / (double)NDEPTH);
    }
}

extern "C" void kernel_launch(void* const* d_in, const int* in_sizes, int n_in,
                              void* d_out, int out_size, void* d_ws, size_t ws_size,
                              hipStream_t stream) {
    const float* x   = (const float*)d_in[0];
    const float* cbs = (const float*)d_in[1];
    float* out = (float*)d_out;
    char* ws = (char*)d_ws;

    double*         resid64  = (double*)(ws);                         // 16,777,216
    unsigned short* chA      = (unsigned short*)(ws + 16777216);      // 16,777,216
    unsigned short* clA      = (unsigned short*)(ws + 33554432);      // 16,777,216
    unsigned short* rhB      = (unsigned short*)(ws + 50331648);      //  4,194,304
    unsigned short* rlB      = (unsigned short*)(ws + 54525952);      //  4,194,304
    double*         cnorm64  = (double*)(ws + 58720256);              //    262,144
    float*          cnorm32  = (float*)(ws + 58982400);               //    131,072
    float*          sM1      = (float*)(ws + 59113472);               //    262,144
    int*            sJ1      = (int*)  (ws + 59375616);               //    262,144
    float*          sM2      = (float*)(ws + 59637760);               //    262,144
    int*            idxbuf   = (int*)  (ws + 59899904);               //     32,768
    int*            flagList = (int*)  (ws + 59932672);               //      4,096
    double*         partD    = (double*)(ws + 59936768);              //     65,536
    int*            partJ    = (int*)  (ws + 60002304);               //     32,768
    int*            flagCount= (int*)  (ws + 60035072);               //         16
    double*         lossSum  = (double*)(ws + 60035088);              //         32

    hipMemsetAsync(lossSum, 0, NDEPTH * sizeof(double), stream);
    cast_kernel<<<NTOK * DIM / 256, 256, 0, stream>>>(x, resid64);
    cnorm_kernel<<<dim3(KARG / 4, NDEPTH), 256, 0, stream>>>(cbs, cnorm64, cnorm32);
    prep_codes<<<NDEPTH * KARG, 256, 0, stream>>>(cbs, chA, clA);
    prep_tokens0<<<NTOK, 256, 0, stream>>>(x, rhB, rlB);

    float* codes_base = out + (size_t)NTOK * DIM + 1;
    for (int d = 0; d < NDEPTH; ++d) {
        const float* cbd = cbs + (size_t)d * KROWS * DIM;
        hipMemsetAsync(flagCount, 0, sizeof(int), stream);
        argmin_mfma<<<32 * NSLICE, 512, 0, stream>>>(chA + (size_t)d * KARG * DIM,
                                                     clA + (size_t)d * KARG * DIM,
                                                     rhB, rlB, cnorm32 + (size_t)d * KARG,
                                                     sM1, sJ1, sM2);
        merge_flag8<<<NTOK / 256, 256, 0, stream>>>(sM1, sJ1, sM2, idxbuf, flagList, flagCount);
        recheck_part<<<FCAP * 8, 256, 0, stream>>>(resid64, cbd, cnorm64 + (size_t)d * KARG,
                                                   flagList, flagCount, partD, partJ);
        recheck_merge<<<FCAP / 256, 256, 0, stream>>>(flagList, flagCount, partD, partJ, idxbuf);
        update_kernel<<<NTOK, 256, 0, stream>>>(x, cbd, idxbuf, resid64, out,
                                                lossSum + d, codes_base + d, rhB, rlB,
                                                d == 0 ? 1 : 0);
    }
    final_kernel<<<1, 64, 0, stream>>>(out, lossSum);
}

// Round 9
// 1321.866 us; speedup vs baseline: 5.2710x; 1.9510x over previous
//
#include <hip/hip_runtime.h>

#define NTOK   8192
#define DIM    256
#define NDEPTH 4
#define KROWS  8193     // storage stride of codebooks input
#define KARG   8192     // argmin domain (padding row dropped)
#define NSLICE 8        // code slices (1024 codes each)
#define FCAP   1024     // flagged-token capacity
#define EPSGAP 3e-3f    // >= 6x worst-case bf16-split distance error

typedef __attribute__((ext_vector_type(8))) short short8v;
typedef __attribute__((ext_vector_type(4))) float float4v;

__device__ __forceinline__ unsigned short f2bf(float f) {
    unsigned int u = __float_as_uint(f);
    unsigned int r = (u + 0x7FFFu + ((u >> 16) & 1u)) >> 16;
    return (unsigned short)r;
}

// fragment index (16x16x32 bf16 MFMA layout, m89-verified family)
// tile-major, 8 k-slices (s) per tile, 64 lanes, 8 halfwords
__device__ __forceinline__ size_t fragIdx(int tile, int s, int lane, int e) {
    return ((((size_t)tile * 8 + s) * 64 + lane) * 8 + e);
}

// ---------------- tokens(x) -> bf16 hi/lo fragments + fp64 residual seed ----------------
__global__ void prep_tokens0(const float* __restrict__ x, unsigned short* __restrict__ rhB,
                             unsigned short* __restrict__ rlB, double* __restrict__ r64) {
    int t = blockIdx.x, i = threadIdx.x;
    float v = x[(size_t)t * DIM + i];
    r64[(size_t)t * DIM + i] = (double)v;
    unsigned short hb = f2bf(v);
    float hf = __uint_as_float(((unsigned int)hb) << 16);
    unsigned short lb = f2bf(v - hf);
    int T = t >> 4, n = t & 15;
    int s = i >> 5, kl = i & 31, g = kl >> 3, e = kl & 7;
    size_t idx = fragIdx(T, s, g * 16 + n, e);
    rhB[idx] = hb;
    rlB[idx] = lb;
}

// ---------------- cnorm fp64 + fp32 ----------------
__global__ void cnorm_kernel(const float* __restrict__ cbs, double* __restrict__ cnorm64,
                             float* __restrict__ cnorm32) {
    int d    = blockIdx.y;
    int row  = blockIdx.x * 4 + (threadIdx.x >> 6);
    int lane = threadIdx.x & 63;
    const float* c = cbs + ((size_t)d * KROWS + row) * DIM;
    float4 v = *(const float4*)(c + lane * 4);
    double s = (double)v.x * v.x + (double)v.y * v.y + (double)v.z * v.z + (double)v.w * v.w;
    #pragma unroll
    for (int o = 32; o > 0; o >>= 1) s += __shfl_down(s, o, 64);
    if (lane == 0) {
        cnorm64[(size_t)d * KARG + row] = s;
        cnorm32[(size_t)d * KARG + row] = (float)s;
    }
}

// ---------------- codes -> bf16 hi/lo fragments (all depths, once) ----------------
__global__ void prep_codes(const float* __restrict__ cbs, unsigned short* __restrict__ chA,
                           unsigned short* __restrict__ clA) {
    int bid = blockIdx.x;              // d*8192 + j
    int d = bid >> 13, j = bid & 8191;
    int i = threadIdx.x;
    float v = cbs[((size_t)d * KROWS + j) * DIM + i];
    unsigned short hb = f2bf(v);
    float hf = __uint_as_float(((unsigned int)hb) << 16);
    unsigned short lb = f2bf(v - hf);
    int CT = j >> 4, m = j & 15;
    int s = i >> 5, kl = i & 31, g = kl >> 3, e = kl & 7;
    size_t base = (size_t)d * KARG * DIM;
    size_t idx = base + fragIdx(CT, s, g * 16 + m, e);
    chA[idx] = hb;
    clA[idx] = lb;
}

// ---------------- MFMA argmin v2: LDS-staged A (dbuf), reg-persistent B ----------------
// grid: 512 = 64 token-groups (128 tok) x 8 slices (1024 codes). slice = blockIdx&7 -> XCD affinity.
__global__ __launch_bounds__(512, 2) void argmin_mfma2(const unsigned short* __restrict__ chA_d,
                                                       const unsigned short* __restrict__ clA_d,
                                                       const unsigned short* __restrict__ rhB,
                                                       const unsigned short* __restrict__ rlB,
                                                       const float* __restrict__ cn32_d,
                                                       float* __restrict__ sM1, int* __restrict__ sJ1,
                                                       float* __restrict__ sM2) {
    __shared__ unsigned short lds[2][2][16384];   // [buf][hi/lo][4CT * 8s * 64lane * 8e] = 128 KB
    const int tid  = threadIdx.x;
    const int wave = tid >> 6, lane = tid & 63;
    const int tg = blockIdx.x >> 3, slice = blockIdx.x & 7;
    const int g4 = lane >> 4, col = lane & 15;
    const float INF = __int_as_float(0x7f800000);

    // persistent B fragments: token tile T = tg*8 + wave (16 tokens)
    const int T = tg * 8 + wave;
    short8v bh[8], bl[8];
    #pragma unroll
    for (int s = 0; s < 8; ++s) {
        bh[s] = *(const short8v*)(rhB + fragIdx(T, s, lane, 0));
        bl[s] = *(const short8v*)(rlB + fragIdx(T, s, lane, 0));
    }

    typedef const __attribute__((address_space(1))) unsigned int GUI;
    typedef __attribute__((address_space(3))) unsigned int LUI;
    // stage cg's 4 code-tiles (64 codes x K=256, hi+lo = 64 KB) into lds[buf]
    auto stage = [&](int buf, int cg) {
        const unsigned short* gh = chA_d + ((size_t)(slice * 64 + cg * 4)) * 4096;
        const unsigned short* gl = clA_d + ((size_t)(slice * 64 + cg * 4)) * 4096;
        #pragma unroll
        for (int p = 0; p < 4; ++p) {
            int off = (p * 512 + tid) * 8;                       // halfwords
            __builtin_amdgcn_global_load_lds((GUI*)(gh + off), (LUI*)(&lds[buf][0][off]), 16, 0, 0);
            __builtin_amdgcn_global_load_lds((GUI*)(gl + off), (LUI*)(&lds[buf][1][off]), 16, 0, 0);
        }
    };

    float M1 = INF, M2 = INF;
    int   J1 = 0;

    stage(0, 0);
    int buf = 0;
    for (int cg = 0; cg < 16; ++cg) {
        // cn loads FIRST (older than stage-issue -> compiler waits vmcnt(8), keeps prefetch alive)
        float4 cn[4];
        #pragma unroll
        for (int ct = 0; ct < 4; ++ct)
            cn[ct] = *(const float4*)(cn32_d + (slice * 64 + cg * 4 + ct) * 16 + g4 * 4);
        // prefetch next cg (unconditional; cg==15 reads adjacent ws bytes, never consumed)
        stage(buf ^ 1, cg + 1);
        // wait: drain to 12 outstanding (= 4 cn + 8 next-stage) -> current buf's 8 landed
        asm volatile("s_waitcnt vmcnt(12)" ::: "memory");
        __builtin_amdgcn_s_barrier();

        float4v acc[4];
        #pragma unroll
        for (int ct = 0; ct < 4; ++ct) acc[ct] = (float4v){0.f, 0.f, 0.f, 0.f};
        #pragma unroll
        for (int s = 0; s < 8; ++s) {
            #pragma unroll
            for (int ct = 0; ct < 4; ++ct) {
                short8v ah = *(const short8v*)&lds[buf][0][((ct * 8 + s) * 64 + lane) * 8];
                short8v al = *(const short8v*)&lds[buf][1][((ct * 8 + s) * 64 + lane) * 8];
                acc[ct] = __builtin_amdgcn_mfma_f32_16x16x32_bf16(ah, bh[s], acc[ct], 0, 0, 0);
                acc[ct] = __builtin_amdgcn_mfma_f32_16x16x32_bf16(ah, bl[s], acc[ct], 0, 0, 0);
                acc[ct] = __builtin_amdgcn_mfma_f32_16x16x32_bf16(al, bh[s], acc[ct], 0, 0, 0);
            }
        }
        // epilogue: dist = cn - 2*acc; running (m1, j1, m2), j ascending
        #pragma unroll
        for (int ct = 0; ct < 4; ++ct) {
            const int jb = (slice * 64 + cg * 4 + ct) * 16 + g4 * 4;
            float dv;
            dv = cn[ct].x - 2.0f * acc[ct][0];
            if (dv < M1) { M2 = M1; M1 = dv; J1 = jb + 0; } else if (dv < M2) M2 = dv;
            dv = cn[ct].y - 2.0f * acc[ct][1];
            if (dv < M1) { M2 = M1; M1 = dv; J1 = jb + 1; } else if (dv < M2) M2 = dv;
            dv = cn[ct].z - 2.0f * acc[ct][2];
            if (dv < M1) { M2 = M1; M1 = dv; J1 = jb + 2; } else if (dv < M2) M2 = dv;
            dv = cn[ct].w - 2.0f * acc[ct][3];
            if (dv < M1) { M2 = M1; M1 = dv; J1 = jb + 3; } else if (dv < M2) M2 = dv;
        }
        __builtin_amdgcn_s_barrier();   // all waves done reading buf before next overwrite cycle
        buf ^= 1;
    }

    // reduce across the 4 lane-groups (g4) holding the same token column
    #pragma unroll
    for (int off = 16; off <= 32; off <<= 1) {
        float om1 = __shfl_xor(M1, off, 64);
        int   oj  = __shfl_xor(J1, off, 64);
        float om2 = __shfl_xor(M2, off, 64);
        if (om1 < M1 || (om1 == M1 && oj < J1)) {
            M2 = fminf(M1, om2); M1 = om1; J1 = oj;
        } else {
            M2 = fminf(M2, om1);
        }
    }
    if (g4 == 0) {
        int t = tg * 128 + wave * 16 + col;
        sM1[slice * NTOK + t] = M1;
        sJ1[slice * NTOK + t] = J1;
        sM2[slice * NTOK + t] = M2;
    }
}

// ---------------- merge 8 slices; always write best guess; flag near-ties ----------------
__global__ void merge_flag8(const float* __restrict__ sM1, const int* __restrict__ sJ1,
                            const float* __restrict__ sM2, int* __restrict__ idxv,
                            int* __restrict__ flagList, int* __restrict__ flagCount) {
    int t = blockIdx.x * 256 + threadIdx.x;
    float m1 = sM1[t], m2 = sM2[t];
    int   j1 = sJ1[t];
    #pragma unroll
    for (int s = 1; s < NSLICE; ++s) {
        float a1 = sM1[s * NTOK + t], a2 = sM2[s * NTOK + t];
        int   aj = sJ1[s * NTOK + t];
        if (a1 < m1) { m2 = fminf(m1, a2); m1 = a1; j1 = aj; }   // slices ascending: strict <
        else         { m2 = fminf(m2, a1); }
    }
    idxv[t] = j1;
    if (m2 - m1 <= EPSGAP) {
        int pos = atomicAdd(flagCount, 1);
        if (pos < FCAP) flagList[pos] = t;
    }
}

// ---------------- exact fp64 recheck, code-parallel: 8 blocks per flagged token ----------------
__global__ __launch_bounds__(256) void recheck_part(const double* __restrict__ rsrc,
                                                    const float* __restrict__ cb,
                                                    const double* __restrict__ cnorm,
                                                    const int* __restrict__ flagList,
                                                    const int* __restrict__ flagCount,
                                                    double* __restrict__ partD,
                                                    int* __restrict__ partJ) {
    const int slot = blockIdx.x >> 3;
    const int cnt  = min(*flagCount, FCAP);
    if (slot >= cnt) return;
    const int range = blockIdx.x & 7;
    const int tid   = threadIdx.x;
    const int tok   = flagList[slot];
    __shared__ double rs[DIM];
    __shared__ double sbest[256];
    __shared__ int    sbidx[256];
    rs[tid] = rsrc[(size_t)tok * DIM + tid];
    __syncthreads();

    double best = 1e300; int bestj = 0;
    for (int q = 0; q < 4; ++q) {
        const int j = range * 1024 + q * 256 + tid;
        const float* c = cb + (size_t)j * DIM;
        double acc = 0.0;
        #pragma unroll 1
        for (int i = 0; i < DIM; i += 4) {
            float4 cv = *(const float4*)(c + i);
            acc = fma((double)cv.w, rs[i + 3],
                  fma((double)cv.z, rs[i + 2],
                  fma((double)cv.y, rs[i + 1],
                  fma((double)cv.x, rs[i + 0], acc))));
        }
        double dist = cnorm[j] - 2.0 * acc;
        if (dist < best) { best = dist; bestj = j; }      // q ascending: strict <
    }
    sbest[tid] = best; sbidx[tid] = bestj;
    __syncthreads();
    for (int s = 128; s > 0; s >>= 1) {
        if (tid < s) {
            double ob = sbest[tid + s]; int oj = sbidx[tid + s];
            if (ob < sbest[tid] || (ob == sbest[tid] && oj < sbidx[tid])) {
                sbest[tid] = ob; sbidx[tid] = oj;
            }
        }
        __syncthreads();
    }
    if (tid == 0) { partD[slot * 8 + range] = sbest[0]; partJ[slot * 8 + range] = sbidx[0]; }
}

__global__ void recheck_merge(const int* __restrict__ flagList, const int* __restrict__ flagCount,
                              const double* __restrict__ partD, const int* __restrict__ partJ,
                              int* __restrict__ idxv) {
    int slot = blockIdx.x * 256 + threadIdx.x;
    int cnt  = min(*flagCount, FCAP);
    if (slot >= cnt) return;
    double best = partD[slot * 8]; int bestj = partJ[slot * 8];
    #pragma unroll
    for (int r = 1; r < 8; ++r) {
        double ob = partD[slot * 8 + r]; int oj = partJ[slot * 8 + r];
        if (ob < best) { best = ob; bestj = oj; }         // ranges ascending: strict <
    }
    idxv[flagList[slot]] = bestj;
}

// ---------------- update: fp64 residual + next-depth bf16 frags + agg/loss/codes ----------------
__global__ void update_kernel(const float* __restrict__ x, const float* __restrict__ cb,
                              const int* __restrict__ idxv, double* __restrict__ resid,
                              float* __restrict__ out, double* __restrict__ lossSum,
                              float* __restrict__ codes_out, unsigned short* __restrict__ rhB,
                              unsigned short* __restrict__ rlB, int is_first) {
    const int t = blockIdx.x;
    const int i = threadIdx.x;
    const int idx = idxv[t];
    const size_t off = (size_t)t * DIM + i;
    float q = cb[(size_t)idx * DIM + i];
    double r_new = resid[off] - (double)q;
    resid[off] = r_new;
    float rv = (float)r_new;
    unsigned short hb = f2bf(rv);
    float hf = __uint_as_float(((unsigned int)hb) << 16);
    unsigned short lb = f2bf(rv - hf);
    {
        int T = t >> 4, n = t & 15;
        int s = i >> 5, kl = i & 31, g = kl >> 3, e = kl & 7;
        size_t fi = fragIdx(T, s, g * 16 + n, e);
        rhB[fi] = hb; rlB[fi] = lb;
    }
    float a_new = is_first ? q : (out[off] + q);    // out doubles as agg (STE: out == agg)
    out[off] = a_new;
    float diff = x[off] - a_new;
    double v = (double)diff * (double)diff;
    #pragma unroll
    for (int o = 32; o > 0; o >>= 1) v += __shfl_down(v, o, 64);
    __shared__ double wsum[4];
    int wid = i >> 6, lane = i & 63;
    if (lane == 0) wsum[wid] = v;
    __syncthreads();
    if (i == 0) {
        atomicAdd(lossSum, wsum[0] + wsum[1] + wsum[2] + wsum[3]);
        codes_out[(size_t)t * NDEPTH] = (float)idx;
    }
}

// ---------------- epilogue: commitment loss scalar ----------------
__global__ void final_kernel(float* __restrict__ out, const double* __restrict__ lossSum) {
    if (threadIdx.x == 0) {
        double s = (lossSum[0] + lossSum[1] + lossSum[2] + lossSum[3]) / (double)((size_t)NTOK * DIM);
        out[(size_t)NTOK * DIM] = (float)(0.25 * s / (double)NDEPTH);
    }
}

extern "C" void kernel_launch(void* const* d_in, const int* in_sizes, int n_in,
                              void* d_out, int out_size, void* d_ws, size_t ws_size,
                              hipStream_t stream) {
    const float* x   = (const float*)d_in[0];
    const float* cbs = (const float*)d_in[1];
    float* out = (float*)d_out;
    char* ws = (char*)d_ws;

    double*         resid64  = (double*)(ws);                         // 16,777,216
    unsigned short* chA      = (unsigned short*)(ws + 16777216);      // 16,777,216
    unsigned short* clA      = (unsigned short*)(ws + 33554432);      // 16,777,216
    unsigned short* rhB      = (unsigned short*)(ws + 50331648);      //  4,194,304
    unsigned short* rlB      = (unsigned short*)(ws + 54525952);      //  4,194,304
    double*         cnorm64  = (double*)(ws + 58720256);              //    262,144
    float*          cnorm32  = (float*)(ws + 58982400);               //    131,072
    float*          sM1      = (float*)(ws + 59113472);               //    262,144
    int*            sJ1      = (int*)  (ws + 59375616);               //    262,144
    float*          sM2      = (float*)(ws + 59637760);               //    262,144
    int*            idxbuf   = (int*)  (ws + 59899904);               //     32,768
    int*            flagList = (int*)  (ws + 59932672);               //      4,096
    double*         partD    = (double*)(ws + 59936768);              //     65,536
    int*            partJ    = (int*)  (ws + 60002304);               //     32,768
    int*            flagCount= (int*)  (ws + 60035072);               //         16
    double*         lossSum  = (double*)(ws + 60035088);              //         32

    hipMemsetAsync(lossSum, 0, NDEPTH * sizeof(double), stream);
    prep_tokens0<<<NTOK, 256, 0, stream>>>(x, rhB, rlB, resid64);
    cnorm_kernel<<<dim3(KARG / 4, NDEPTH), 256, 0, stream>>>(cbs, cnorm64, cnorm32);
    prep_codes<<<NDEPTH * KARG, 256, 0, stream>>>(cbs, chA, clA);

    float* codes_base = out + (size_t)NTOK * DIM + 1;
    for (int d = 0; d < NDEPTH; ++d) {
        const float* cbd = cbs + (size_t)d * KROWS * DIM;
        hipMemsetAsync(flagCount, 0, sizeof(int), stream);
        argmin_mfma2<<<512, 512, 0, stream>>>(chA + (size_t)d * KARG * DIM,
                                              clA + (size_t)d * KARG * DIM,
                                              rhB, rlB, cnorm32 + (size_t)d * KARG,
                                              sM1, sJ1, sM2);
        merge_flag8<<<NTOK / 256, 256, 0, stream>>>(sM1, sJ1, sM2, idxbuf, flagList, flagCount);
        recheck_part<<<FCAP * 8, 256, 0, stream>>>(resid64, cbd, cnorm64 + (size_t)d * KARG,
                                                   flagList, flagCount, partD, partJ);
        recheck_merge<<<FCAP / 256, 256, 0, stream>>>(flagList, flagCount, partD, partJ, idxbuf);
        update_kernel<<<NTOK, 256, 0, stream>>>(x, cbd, idxbuf, resid64, out,
                                                lossSum + d, codes_base + d, rhB, rlB,
                                                d == 0 ? 1 : 0);
    }
    final_kernel<<<1, 64, 0, stream>>>(out, lossSum);
}

// Round 10
// 1216.989 us; speedup vs baseline: 5.7252x; 1.0862x over previous
//
#include <hip/hip_runtime.h>

#define NTOK   8192
#define DIM    256
#define NDEPTH 4
#define KROWS  8193     // storage stride of codebooks input
#define KARG   8192     // argmin domain (padding row dropped)
#define NSLICE 8        // code slices (1024 codes each)
#define FCAP   1024     // flagged-token capacity
#define EPSGAP 3e-3f    // >= 6x worst-case bf16-split distance error

typedef __attribute__((ext_vector_type(8))) short short8v;
typedef __attribute__((ext_vector_type(4))) float float4v;

__device__ __forceinline__ unsigned short f2bf(float f) {
    unsigned int u = __float_as_uint(f);
    unsigned int r = (u + 0x7FFFu + ((u >> 16) & 1u)) >> 16;
    return (unsigned short)r;
}

// fragment index (16x16x32 bf16 MFMA layout, m89-verified family)
__device__ __forceinline__ size_t fragIdx(int tile, int s, int lane, int e) {
    return ((((size_t)tile * 8 + s) * 64 + lane) * 8 + e);
}

// ---------------- fused prologue: token prep | code prep + cnorm ----------------
__global__ void prep_all(const float* __restrict__ x, const float* __restrict__ cbs,
                         unsigned short* __restrict__ rhB, unsigned short* __restrict__ rlB,
                         double* __restrict__ r64, unsigned short* __restrict__ chA,
                         unsigned short* __restrict__ clA, double* __restrict__ cnorm64,
                         float* __restrict__ cnorm32) {
    const int bid = blockIdx.x;
    const int i = threadIdx.x;
    if (bid < NTOK) {
        int t = bid;
        float v = x[(size_t)t * DIM + i];
        r64[(size_t)t * DIM + i] = (double)v;
        unsigned short hb = f2bf(v);
        float hf = __uint_as_float(((unsigned int)hb) << 16);
        unsigned short lb = f2bf(v - hf);
        int T = t >> 4, n = t & 15;
        int s = i >> 5, kl = i & 31, g = kl >> 3, e = kl & 7;
        size_t idx = fragIdx(T, s, g * 16 + n, e);
        rhB[idx] = hb;
        rlB[idx] = lb;
    } else {
        int cid = bid - NTOK;                    // d*8192 + j
        int d = cid >> 13, j = cid & 8191;
        float v = cbs[((size_t)d * KROWS + j) * DIM + i];
        unsigned short hb = f2bf(v);
        float hf = __uint_as_float(((unsigned int)hb) << 16);
        unsigned short lb = f2bf(v - hf);
        int CT = j >> 4, m = j & 15;
        int s = i >> 5, kl = i & 31, g = kl >> 3, e = kl & 7;
        size_t base = (size_t)d * KARG * DIM;
        size_t idx = base + fragIdx(CT, s, g * 16 + m, e);
        chA[idx] = hb;
        clA[idx] = lb;
        // cnorm: fp64 block reduction of v*v
        double sq = (double)v * (double)v;
        #pragma unroll
        for (int o = 32; o > 0; o >>= 1) sq += __shfl_down(sq, o, 64);
        __shared__ double wsum[4];
        int wid = i >> 6, lane = i & 63;
        if (lane == 0) wsum[wid] = sq;
        __syncthreads();
        if (i == 0) {
            double sv = wsum[0] + wsum[1] + wsum[2] + wsum[3];
            cnorm64[(size_t)d * KARG + j] = sv;
            cnorm32[(size_t)d * KARG + j] = (float)sv;
        }
    }
}

// ---------------- MFMA argmin v3: LDS-staged A (dbuf), reg-persistent B, tt=2 ----------------
// grid: 256 = 32 token-groups (256 tok) x 8 slices (1024 codes). slice = blockIdx&7 -> XCD affinity.
__global__ __launch_bounds__(512, 2) void argmin_mfma3(const unsigned short* __restrict__ chA_d,
                                                       const unsigned short* __restrict__ clA_d,
                                                       const unsigned short* __restrict__ rhB,
                                                       const unsigned short* __restrict__ rlB,
                                                       const float* __restrict__ cn32_d,
                                                       float* __restrict__ sM1, int* __restrict__ sJ1,
                                                       float* __restrict__ sM2) {
    __shared__ unsigned short lds[2][2][16384];   // [buf][hi/lo][4CT * 8s * 64lane * 8e] = 128 KB
    const int tid  = threadIdx.x;
    const int wave = tid >> 6, lane = tid & 63;
    const int tg = blockIdx.x >> 3, slice = blockIdx.x & 7;
    const int g4 = lane >> 4, col = lane & 15;
    const float INF = __int_as_float(0x7f800000);

    // persistent B fragments: two token tiles T0, T0+1 (32 tokens/wave)
    const int T0 = tg * 16 + wave * 2;
    short8v bh0[8], bl0[8], bh1[8], bl1[8];
    #pragma unroll
    for (int s = 0; s < 8; ++s) {
        bh0[s] = *(const short8v*)(rhB + fragIdx(T0,     s, lane, 0));
        bl0[s] = *(const short8v*)(rlB + fragIdx(T0,     s, lane, 0));
        bh1[s] = *(const short8v*)(rhB + fragIdx(T0 + 1, s, lane, 0));
        bl1[s] = *(const short8v*)(rlB + fragIdx(T0 + 1, s, lane, 0));
    }

    typedef const __attribute__((address_space(1))) unsigned int GUI;
    typedef __attribute__((address_space(3))) unsigned int LUI;
    auto stage = [&](int buf, int cg) {
        const unsigned short* gh = chA_d + ((size_t)(slice * 64 + cg * 4)) * 4096;
        const unsigned short* gl = clA_d + ((size_t)(slice * 64 + cg * 4)) * 4096;
        #pragma unroll
        for (int p = 0; p < 4; ++p) {
            int off = (p * 512 + tid) * 8;                       // halfwords
            __builtin_amdgcn_global_load_lds((GUI*)(gh + off), (LUI*)(&lds[buf][0][off]), 16, 0, 0);
            __builtin_amdgcn_global_load_lds((GUI*)(gl + off), (LUI*)(&lds[buf][1][off]), 16, 0, 0);
        }
    };

    float M1[2] = {INF, INF}, M2[2] = {INF, INF};
    int   J1[2] = {0, 0};

    stage(0, 0);
    int buf = 0;
    for (int cg = 0; cg < 16; ++cg) {
        // cn loads FIRST (older than stage-issue -> waits land at vmcnt(8+4), prefetch stays alive)
        float4 cn[4];
        #pragma unroll
        for (int ct = 0; ct < 4; ++ct)
            cn[ct] = *(const float4*)(cn32_d + (slice * 64 + cg * 4 + ct) * 16 + g4 * 4);
        stage(buf ^ 1, cg + 1);   // unconditional; cg==15 prefetches adjacent ws bytes, never consumed
        asm volatile("s_waitcnt vmcnt(12)" ::: "memory");   // 4 cn + 8 next-stage outstanding
        __builtin_amdgcn_s_barrier();

        float4v acc[4][2];
        #pragma unroll
        for (int ct = 0; ct < 4; ++ct) {
            acc[ct][0] = (float4v){0.f, 0.f, 0.f, 0.f};
            acc[ct][1] = (float4v){0.f, 0.f, 0.f, 0.f};
        }
        #pragma unroll
        for (int s = 0; s < 8; ++s) {
            #pragma unroll
            for (int ct = 0; ct < 4; ++ct) {
                short8v ah = *(const short8v*)&lds[buf][0][((ct * 8 + s) * 64 + lane) * 8];
                short8v al = *(const short8v*)&lds[buf][1][((ct * 8 + s) * 64 + lane) * 8];
                acc[ct][0] = __builtin_amdgcn_mfma_f32_16x16x32_bf16(ah, bh0[s], acc[ct][0], 0, 0, 0);
                acc[ct][0] = __builtin_amdgcn_mfma_f32_16x16x32_bf16(ah, bl0[s], acc[ct][0], 0, 0, 0);
                acc[ct][0] = __builtin_amdgcn_mfma_f32_16x16x32_bf16(al, bh0[s], acc[ct][0], 0, 0, 0);
                acc[ct][1] = __builtin_amdgcn_mfma_f32_16x16x32_bf16(ah, bh1[s], acc[ct][1], 0, 0, 0);
                acc[ct][1] = __builtin_amdgcn_mfma_f32_16x16x32_bf16(ah, bl1[s], acc[ct][1], 0, 0, 0);
                acc[ct][1] = __builtin_amdgcn_mfma_f32_16x16x32_bf16(al, bh1[s], acc[ct][1], 0, 0, 0);
            }
        }
        // epilogue: dist = cn - 2*acc; running (m1, j1, m2); j ascending within lane
        #pragma unroll
        for (int ct = 0; ct < 4; ++ct) {
            const int jb = (slice * 64 + cg * 4 + ct) * 16 + g4 * 4;
            #pragma unroll
            for (int tt = 0; tt < 2; ++tt) {
                float dv;
                dv = cn[ct].x - 2.0f * acc[ct][tt][0];
                if (dv < M1[tt]) { M2[tt] = M1[tt]; M1[tt] = dv; J1[tt] = jb + 0; } else if (dv < M2[tt]) M2[tt] = dv;
                dv = cn[ct].y - 2.0f * acc[ct][tt][1];
                if (dv < M1[tt]) { M2[tt] = M1[tt]; M1[tt] = dv; J1[tt] = jb + 1; } else if (dv < M2[tt]) M2[tt] = dv;
                dv = cn[ct].z - 2.0f * acc[ct][tt][2];
                if (dv < M1[tt]) { M2[tt] = M1[tt]; M1[tt] = dv; J1[tt] = jb + 2; } else if (dv < M2[tt]) M2[tt] = dv;
                dv = cn[ct].w - 2.0f * acc[ct][tt][3];
                if (dv < M1[tt]) { M2[tt] = M1[tt]; M1[tt] = dv; J1[tt] = jb + 3; } else if (dv < M2[tt]) M2[tt] = dv;
            }
        }
        __builtin_amdgcn_s_barrier();   // all waves done reading buf before next overwrite
        buf ^= 1;
    }

    // reduce across the 4 lane-groups (g4) holding the same token column
    #pragma unroll
    for (int off = 16; off <= 32; off <<= 1) {
        #pragma unroll
        for (int tt = 0; tt < 2; ++tt) {
            float om1 = __shfl_xor(M1[tt], off, 64);
            int   oj  = __shfl_xor(J1[tt], off, 64);
            float om2 = __shfl_xor(M2[tt], off, 64);
            if (om1 < M1[tt] || (om1 == M1[tt] && oj < J1[tt])) {
                M2[tt] = fminf(M1[tt], om2); M1[tt] = om1; J1[tt] = oj;
            } else {
                M2[tt] = fminf(M2[tt], om1);
            }
        }
    }
    if (g4 == 0) {
        #pragma unroll
        for (int tt = 0; tt < 2; ++tt) {
            int t = (T0 + tt) * 16 + col;
            sM1[slice * NTOK + t] = M1[tt];
            sJ1[slice * NTOK + t] = J1[tt];
            sM2[slice * NTOK + t] = M2[tt];
        }
    }
}

// ---------------- merge 8 slices; best guess + flag near-ties (slot map) ----------------
__global__ void merge_flag8(const float* __restrict__ sM1, const int* __restrict__ sJ1,
                            const float* __restrict__ sM2, int* __restrict__ idxv,
                            int* __restrict__ flagList, int* __restrict__ flagCount,
                            int* __restrict__ flagSlot) {
    int t = blockIdx.x * 256 + threadIdx.x;
    float m1 = sM1[t], m2 = sM2[t];
    int   j1 = sJ1[t];
    #pragma unroll
    for (int s = 1; s < NSLICE; ++s) {
        float a1 = sM1[s * NTOK + t], a2 = sM2[s * NTOK + t];
        int   aj = sJ1[s * NTOK + t];
        if (a1 < m1) { m2 = fminf(m1, a2); m1 = a1; j1 = aj; }   // slices ascending: strict <
        else         { m2 = fminf(m2, a1); }
    }
    idxv[t] = j1;
    int slot = -1;
    if (m2 - m1 <= EPSGAP) {
        slot = atomicAdd(flagCount, 1);
        if (slot < FCAP) flagList[slot] = t;
    }
    flagSlot[t] = slot;    // -1 or >=FCAP => prefilter result stands
}

// ---------------- exact fp64 recheck, code-parallel: 8 blocks per flagged token ----------------
__global__ __launch_bounds__(256) void recheck_part(const double* __restrict__ rsrc,
                                                    const float* __restrict__ cb,
                                                    const double* __restrict__ cnorm,
                                                    const int* __restrict__ flagList,
                                                    const int* __restrict__ flagCount,
                                                    double* __restrict__ partD,
                                                    int* __restrict__ partJ) {
    const int slot = blockIdx.x >> 3;
    const int cnt  = min(*flagCount, FCAP);
    if (slot >= cnt) return;
    const int range = blockIdx.x & 7;
    const int tid   = threadIdx.x;
    const int tok   = flagList[slot];
    __shared__ double rs[DIM];
    __shared__ double sbest[256];
    __shared__ int    sbidx[256];
    rs[tid] = rsrc[(size_t)tok * DIM + tid];
    __syncthreads();

    double best = 1e300; int bestj = 0;
    for (int q = 0; q < 4; ++q) {
        const int j = range * 1024 + q * 256 + tid;
        const float* c = cb + (size_t)j * DIM;
        double acc = 0.0;
        #pragma unroll 1
        for (int i = 0; i < DIM; i += 4) {
            float4 cv = *(const float4*)(c + i);
            acc = fma((double)cv.w, rs[i + 3],
                  fma((double)cv.z, rs[i + 2],
                  fma((double)cv.y, rs[i + 1],
                  fma((double)cv.x, rs[i + 0], acc))));
        }
        double dist = cnorm[j] - 2.0 * acc;
        if (dist < best) { best = dist; bestj = j; }      // q ascending: strict <
    }
    sbest[tid] = best; sbidx[tid] = bestj;
    __syncthreads();
    for (int s = 128; s > 0; s >>= 1) {
        if (tid < s) {
            double ob = sbest[tid + s]; int oj = sbidx[tid + s];
            if (ob < sbest[tid] || (ob == sbest[tid] && oj < sbidx[tid])) {
                sbest[tid] = ob; sbidx[tid] = oj;
            }
        }
        __syncthreads();
    }
    if (tid == 0) { partD[slot * 8 + range] = sbest[0]; partJ[slot * 8 + range] = sbidx[0]; }
}

// ---------------- update: inline recheck-merge + fp64 residual + next-depth frags + loss ----------------
__global__ void update_kernel(const float* __restrict__ x, const float* __restrict__ cb,
                              const int* __restrict__ idxv, const int* __restrict__ flagSlot,
                              const double* __restrict__ partD, const int* __restrict__ partJ,
                              double* __restrict__ resid, float* __restrict__ out,
                              double* __restrict__ lossSum, float* __restrict__ codes_out,
                              unsigned short* __restrict__ rhB, unsigned short* __restrict__ rlB,
                              int is_first) {
    const int t = blockIdx.x;
    const int i = threadIdx.x;
    int idx = idxv[t];
    const int slot = flagSlot[t];
    if (slot >= 0 && slot < FCAP) {                 // fp64 recheck overrides (8 broadcast loads)
        double best = partD[slot * 8]; int bj = partJ[slot * 8];
        #pragma unroll
        for (int r = 1; r < 8; ++r) {
            double ob = partD[slot * 8 + r]; int oj = partJ[slot * 8 + r];
            if (ob < best) { best = ob; bj = oj; }   // ranges ascending: strict <
        }
        idx = bj;
    }
    const size_t off = (size_t)t * DIM + i;
    float q = cb[(size_t)idx * DIM + i];
    double r_new = resid[off] - (double)q;
    resid[off] = r_new;
    float rv = (float)r_new;
    unsigned short hb = f2bf(rv);
    float hf = __uint_as_float(((unsigned int)hb) << 16);
    unsigned short lb = f2bf(rv - hf);
    {
        int T = t >> 4, n = t & 15;
        int s = i >> 5, kl = i & 31, g = kl >> 3, e = kl & 7;
        size_t fi = fragIdx(T, s, g * 16 + n, e);
        rhB[fi] = hb; rlB[fi] = lb;
    }
    float a_new = is_first ? q : (out[off] + q);    // out doubles as agg (STE: out == agg)
    out[off] = a_new;
    float diff = x[off] - a_new;
    double v = (double)diff * (double)diff;
    #pragma unroll
    for (int o = 32; o > 0; o >>= 1) v += __shfl_down(v, o, 64);
    __shared__ double wsum[4];
    int wid = i >> 6, lane = i & 63;
    if (lane == 0) wsum[wid] = v;
    __syncthreads();
    if (i == 0) {
        atomicAdd(lossSum, wsum[0] + wsum[1] + wsum[2] + wsum[3]);
        codes_out[(size_t)t * NDEPTH] = (float)idx;
    }
}

// ---------------- epilogue: commitment loss scalar ----------------
__global__ void final_kernel(float* __restrict__ out, const double* __restrict__ lossSum) {
    if (threadIdx.x == 0) {
        double s = (lossSum[0] + lossSum[1] + lossSum[2] + lossSum[3]) / (double)((size_t)NTOK * DIM);
        out[(size_t)NTOK * DIM] = (float)(0.25 * s / (double)NDEPTH);
    }
}

extern "C" void kernel_launch(void* const* d_in, const int* in_sizes, int n_in,
                              void* d_out, int out_size, void* d_ws, size_t ws_size,
                              hipStream_t stream) {
    const float* x   = (const float*)d_in[0];
    const float* cbs = (const float*)d_in[1];
    float* out = (float*)d_out;
    char* ws = (char*)d_ws;

    double*         resid64  = (double*)(ws);                         // 16,777,216
    unsigned short* chA      = (unsigned short*)(ws + 16777216);      // 16,777,216
    unsigned short* clA      = (unsigned short*)(ws + 33554432);      // 16,777,216
    unsigned short* rhB      = (unsigned short*)(ws + 50331648);      //  4,194,304
    unsigned short* rlB      = (unsigned short*)(ws + 54525952);      //  4,194,304
    double*         cnorm64  = (double*)(ws + 58720256);              //    262,144
    float*          cnorm32  = (float*)(ws + 58982400);               //    131,072
    float*          sM1      = (float*)(ws + 59113472);               //    262,144
    int*            sJ1      = (int*)  (ws + 59375616);               //    262,144
    float*          sM2      = (float*)(ws + 59637760);               //    262,144
    int*            idxbuf   = (int*)  (ws + 59899904);               //     32,768
    int*            flagSlot = (int*)  (ws + 59932672);               //     32,768
    int*            flagList = (int*)  (ws + 59965440);               //      4,096
    double*         partD    = (double*)(ws + 59969536);              //     65,536
    int*            partJ    = (int*)  (ws + 60035072);               //     32,768
    int*            flagCount= (int*)  (ws + 60067840);               //  16 (int[4])
    double*         lossSum  = (double*)(ws + 60067856);              //  32

    hipMemsetAsync(flagCount, 0, 48, stream);    // flagCount[4] + lossSum[4]
    prep_all<<<NTOK + NDEPTH * KARG, 256, 0, stream>>>(x, cbs, rhB, rlB, resid64,
                                                       chA, clA, cnorm64, cnorm32);

    float* codes_base = out + (size_t)NTOK * DIM + 1;
    for (int d = 0; d < NDEPTH; ++d) {
        const float* cbd = cbs + (size_t)d * KROWS * DIM;
        argmin_mfma3<<<256, 512, 0, stream>>>(chA + (size_t)d * KARG * DIM,
                                              clA + (size_t)d * KARG * DIM,
                                              rhB, rlB, cnorm32 + (size_t)d * KARG,
                                              sM1, sJ1, sM2);
        merge_flag8<<<NTOK / 256, 256, 0, stream>>>(sM1, sJ1, sM2, idxbuf,
                                                    flagList, flagCount + d, flagSlot);
        recheck_part<<<FCAP * 8, 256, 0, stream>>>(resid64, cbd, cnorm64 + (size_t)d * KARG,
                                                   flagList, flagCount + d, partD, partJ);
        update_kernel<<<NTOK, 256, 0, stream>>>(x, cbd, idxbuf, flagSlot, partD, partJ,
                                                resid64, out, lossSum + d, codes_base + d,
                                                rhB, rlB, d == 0 ? 1 : 0);
    }
    final_kernel<<<1, 64, 0, stream>>>(out, lossSum);
}